// Round 1
// baseline (48.472 us; speedup 1.0000x reference)
//
#include <hip/hip_runtime.h>
#include <math.h>

#define SEQ 4096
#define NWAVE 4     // waves per block
#define XB 128      // blocks per batch

__global__ __launch_bounds__(256) void fused_model(const int* __restrict__ tokens,
                                                   const float* __restrict__ cptr,
                                                   float* __restrict__ out) {
  __shared__ float kx[SEQ];
  __shared__ float ky[SEQ];
  __shared__ float vv[SEQ];
  __shared__ float stab0[10], stab1[10], salpha[10], sv[10], sq0[10], sq1[10];

  const int tid = threadIdx.x;
  const int b = blockIdx.y;
  const float cs = cptr[0];

  // Derived constants in double, then cast to f32 exactly like Python/jax weak scalars.
  const double omega_d = 2.0 * M_PI / 19.0;
  const double phi_d = omega_d * 10.3;
  const double amp_d = log(10.0) / (cos(omega_d * 0.3) - cos(omega_d * 0.7));
  const double qkns_d = sqrt(amp_d / sqrt(2.0));
  const double attn_scale_d = (1.0 / sqrt(2.0)) * qkns_d * qkns_d;
  const float omega_f = (float)omega_d;
  const float c1 = (float)cos(phi_d);
  const float ns1 = (float)(-sin(phi_d));
  // fold log2(e) so we can use exp2f; softmax is invariant to the max-shift constant
  const float S2 = (float)attn_scale_d * 1.4426950408889634f;
  const float vfac = (float)(-22.0 / sqrt(2.0));

  if (tid < 10) {
    float d = (float)tid;
    float h0 = cs - d * d / cs;
    float h1 = -d;
    float inv = rsqrtf((h0 * h0 + h1 * h1) * 0.5f + 1e-6f);
    float x0 = h0 * inv, x1 = h1 * inv;
    stab0[tid] = h0;
    stab1[tid] = h1;
    salpha[tid] = x0 * rsqrtf((x0 * x0) * 0.5f + 1e-6f);
    sv[tid] = x1 * (vfac * cs);
    float q0 = x0 * c1, q1 = x0 * ns1;
    float invq = rsqrtf((q0 * q0 + q1 * q1) * 0.5f + 1e-6f);
    sq0[tid] = q0 * invq;
    sq1[tid] = q1 * invq;
  }
  __syncthreads();

  // Phase A: stage roped K and V for the whole batch into LDS.
  const int* tb = tokens + b * SEQ;
  for (int j = tid; j < SEQ; j += 256) {
    int d = tb[j];
    float th = (float)j * omega_f;
    float st, ct;
    sincosf(th, &st, &ct);
    float al = salpha[d];
    kx[j] = al * ct;
    ky[j] = al * st;
    vv[j] = sv[d];
  }
  __syncthreads();

  const int wid = tid >> 6;
  const int lane = tid & 63;
  const int gw = blockIdx.x * NWAVE + wid;   // 0..511 within batch
  const int stride = XB * NWAVE;             // 512

  for (int t = 0; t < SEQ / (XB * NWAVE); ++t) {
    const int i = gw + stride * t;
    const int di = tb[i];
    float th = (float)i * omega_f;
    float st, ct;
    sincosf(th, &st, &ct);
    const float qx = (sq0[di] * ct - sq1[di] * st) * S2;
    const float qy = (sq0[di] * st + sq1[di] * ct) * S2;

    // pass 1: row max (in log2 space)
    float m = -INFINITY;
    for (int j = lane; j <= i; j += 64) {
      float l = fmaf(qx, kx[j], qy * ky[j]);
      m = fmaxf(m, l);
    }
#pragma unroll
    for (int off = 32; off; off >>= 1) m = fmaxf(m, __shfl_xor(m, off));

    // pass 2: weighted sums
    float num = 0.f, den = 0.f;
    for (int j = lane; j <= i; j += 64) {
      float l = fmaf(qx, kx[j], qy * ky[j]);
      float e = exp2f(l - m);
      den += e;
      num = fmaf(e, vv[j], num);
    }
#pragma unroll
    for (int off = 32; off; off >>= 1) {
      num += __shfl_xor(num, off);
      den += __shfl_xor(den, off);
    }
    const float o0 = num / den;

    // Elementwise epilogue (mirrors reference fp32 op order)
    const float h0 = stab0[di];
    const float h1 = stab1[di];
    const float h1a = h1 + o0;
    const float inv2 = rsqrtf((h0 * h0 + h1a * h1a) * 0.5f + 1e-6f);
    const float n0 = h0 * inv2, n1 = h1a * inv2;
    const float aa = -12.032f * cs;
    const float gc = 128.0f * cs;
    const float g0 = n0 * aa + n1 * gc;
    const float g1 = n0 * (aa - gc / cs) + n1 * gc;
    const float m0 = (g0 / (1.f + expf(-g0))) * n0;
    const float m1 = (g1 / (1.f + expf(-g1))) * n0;
    const float y1 = 0.390625f * (m1 - m0);
    const float h1b = h1a + y1;
    const float inv3 = rsqrtf((h0 * h0 + h1b * h1b) * 0.5f + 1e-6f);
    const float nw0 = (0.1f * cs) / 1.41421356237309515f;
    const float nw1 = -cs / 70.7106781186547524f;
    const float r0 = h0 * inv3 * nw0;
    const float r1 = h1b * inv3 * nw1;

    if (lane < 10) {
      out[(size_t)(b * SEQ + i) * 10 + lane] = r0 * stab0[lane] + r1 * stab1[lane];
    }
  }
}

extern "C" void kernel_launch(void* const* d_in, const int* in_sizes, int n_in,
                              void* d_out, int out_size, void* d_ws, size_t ws_size,
                              hipStream_t stream) {
  const int* tokens = (const int*)d_in[0];
  const float* c = (const float*)d_in[1];
  float* out = (float*)d_out;
  const int batches = in_sizes[0] / SEQ;   // 4
  dim3 grid(XB, batches);
  fused_model<<<grid, 256, 0, stream>>>(tokens, c, out);
}

// Round 2
// 18.249 us; speedup vs baseline: 2.6561x; 2.6561x over previous
//
#include <hip/hip_runtime.h>
#include <math.h>

#define SEQ 4096
#define RROWS 32          // rows per block
#define NB 192            // 190 buckets (10 tokens x 19 phases), padded to 192

__global__ __launch_bounds__(256) void fused_model(const int* __restrict__ tokens,
                                                   const float* __restrict__ cptr,
                                                   float* __restrict__ out) {
  __shared__ float bkx[NB], bky[NB], bv[NB];
  __shared__ int   cnt[NB];
  __shared__ float kxl[RROWS], kyl[RROWS], vl[RROWS];
  __shared__ int   dl[RROWS];
  __shared__ float stab0[10], stab1[10], salpha[10], sv[10], sq0[10], sq1[10];

  const int tid = threadIdx.x;
  const int b = blockIdx.y;
  const int i0 = blockIdx.x * RROWS;
  const float cs = cptr[0];

  // Derived constants (double, folded at compile time where possible)
  const double omega_d = 2.0 * M_PI / 19.0;
  const double phi_d = omega_d * 10.3;
  const double amp_d = log(10.0) / (cos(omega_d * 0.3) - cos(omega_d * 0.7));
  const double qkns_d = sqrt(amp_d / sqrt(2.0));
  const double attn_scale_d = (1.0 / sqrt(2.0)) * qkns_d * qkns_d;
  const float omega_f = (float)omega_d;
  const float c1 = (float)cos(phi_d);
  const float ns1 = (float)(-sin(phi_d));
  const float S2 = (float)attn_scale_d * 1.4426950408889634f;  // fold log2(e): use exp2
  const float vfac = (float)(-22.0 / sqrt(2.0));

  if (tid < 10) {
    float d = (float)tid;
    float h0 = cs - d * d / cs;
    float h1 = -d;
    float inv = rsqrtf((h0 * h0 + h1 * h1) * 0.5f + 1e-6f);
    float x0 = h0 * inv, x1 = h1 * inv;
    stab0[tid] = h0;
    stab1[tid] = h1;
    salpha[tid] = x0 * rsqrtf((x0 * x0) * 0.5f + 1e-6f);
    sv[tid] = x1 * (vfac * cs);
    float q0 = x0 * c1, q1 = x0 * ns1;
    float invq = rsqrtf((q0 * q0 + q1 * q1) * 0.5f + 1e-6f);
    sq0[tid] = q0 * invq;
    sq1[tid] = q1 * invq;
  }
  __syncthreads();

  // Bucket tables: bucket = d*19 + r, representative phase = fl(r * omega_f)
  if (tid < NB) {
    cnt[tid] = 0;
    if (tid < 190) {
      int d = tid / 19;
      int r = tid - d * 19;
      float st, ct;
      sincosf((float)r * omega_f, &st, &ct);
      float al = salpha[d];
      bkx[tid] = al * ct;
      bky[tid] = al * st;
      bv[tid] = sv[d];
    } else {
      bkx[tid] = 0.f; bky[tid] = 0.f; bv[tid] = 0.f;
    }
  }
  __syncthreads();

  // Base histogram over j < i0, plus exact staging of the local 32 keys.
  const int* tb = tokens + b * SEQ;
  for (int j = tid; j < i0; j += 256) {
    int d = tb[j];
    int r = j % 19;
    atomicAdd(&cnt[d * 19 + r], 1);
  }
  if (tid < RROWS) {
    int j = i0 + tid;
    int d = tb[j];
    float st, ct;
    sincosf((float)j * omega_f, &st, &ct);
    float al = salpha[d];
    kxl[tid] = al * ct;
    kyl[tid] = al * st;
    vl[tid] = sv[d];
    dl[tid] = d;
  }
  __syncthreads();

  const int wid = tid >> 6;
  const int lane = tid & 63;
  const int b0 = lane, b1 = lane + 64, b2 = lane + 128;  // all < NB

  for (int rr = wid; rr < RROWS; rr += 4) {
    const int i = i0 + rr;
    const int di = dl[rr];
    float st, ct;
    sincosf((float)i * omega_f, &st, &ct);
    const float qx = (sq0[di] * ct - sq1[di] * st) * S2;
    const float qy = (sq0[di] * st + sq1[di] * ct) * S2;

    // logits: 3 bucket reps + 1 exact local key per lane
    const int c0 = cnt[b0], c1c = cnt[b1], c2 = cnt[b2];
    const float l0 = fmaf(qx, bkx[b0], qy * bky[b0]);
    const float l1 = fmaf(qx, bkx[b1], qy * bky[b1]);
    const float l2 = fmaf(qx, bkx[b2], qy * bky[b2]);
    const bool loc = (lane <= rr);
    const float l3 = loc ? fmaf(qx, kxl[lane], qy * kyl[lane]) : -INFINITY;
    const float v3 = loc ? vl[lane] : 0.f;

    // row max over NON-EMPTY buckets + local tail (empty buckets excluded: guards NaN)
    float m = fmaxf(fmaxf(c0 ? l0 : -INFINITY, c1c ? l1 : -INFINITY),
                    fmaxf(c2 ? l2 : -INFINITY, l3));
#pragma unroll
    for (int off = 32; off; off >>= 1) m = fmaxf(m, __shfl_xor(m, off));

    const float e0 = c0 ? exp2f(l0 - m) * (float)c0 : 0.f;
    const float e1 = c1c ? exp2f(l1 - m) * (float)c1c : 0.f;
    const float e2 = c2 ? exp2f(l2 - m) * (float)c2 : 0.f;
    const float e3 = loc ? exp2f(l3 - m) : 0.f;
    float den = (e0 + e1) + (e2 + e3);
    float num = fmaf(e0, bv[b0], fmaf(e1, bv[b1], fmaf(e2, bv[b2], e3 * v3)));
#pragma unroll
    for (int off = 32; off; off >>= 1) {
      num += __shfl_xor(num, off);
      den += __shfl_xor(den, off);
    }
    const float o0 = num / den;

    // Elementwise epilogue (identical fp32 op order to the passing R1 kernel)
    const float h0 = stab0[di];
    const float h1 = stab1[di];
    const float h1a = h1 + o0;
    const float inv2 = rsqrtf((h0 * h0 + h1a * h1a) * 0.5f + 1e-6f);
    const float n0 = h0 * inv2, n1 = h1a * inv2;
    const float aa = -12.032f * cs;
    const float gc = 128.0f * cs;
    const float g0 = n0 * aa + n1 * gc;
    const float g1 = n0 * (aa - gc / cs) + n1 * gc;
    const float m0 = (g0 / (1.f + expf(-g0))) * n0;
    const float m1 = (g1 / (1.f + expf(-g1))) * n0;
    const float y1 = 0.390625f * (m1 - m0);
    const float h1b = h1a + y1;
    const float inv3 = rsqrtf((h0 * h0 + h1b * h1b) * 0.5f + 1e-6f);
    const float nw0 = (0.1f * cs) / 1.41421356237309515f;
    const float nw1 = -cs / 70.7106781186547524f;
    const float r0 = h0 * inv3 * nw0;
    const float r1 = h1b * inv3 * nw1;

    if (lane < 10) {
      out[(size_t)(b * SEQ + i) * 10 + lane] = r0 * stab0[lane] + r1 * stab1[lane];
    }
  }
}

extern "C" void kernel_launch(void* const* d_in, const int* in_sizes, int n_in,
                              void* d_out, int out_size, void* d_ws, size_t ws_size,
                              hipStream_t stream) {
  const int* tokens = (const int*)d_in[0];
  const float* c = (const float*)d_in[1];
  float* out = (float*)d_out;
  const int batches = in_sizes[0] / SEQ;   // 4
  dim3 grid(SEQ / RROWS, batches);         // 128 x 4 = 512 blocks
  fused_model<<<grid, 256, 0, stream>>>(tokens, c, out);
}

// Round 3
// 14.564 us; speedup vs baseline: 3.3283x; 1.2531x over previous
//
#include <hip/hip_runtime.h>
#include <math.h>

#define SEQ 4096
#define RROWS 64          // rows per block, one per lane
#define NB 192            // 190 buckets (10 tokens x 19 phases), padded
#define GROUP 48          // buckets per wave (4 waves x 48 = 192)

__global__ __launch_bounds__(256) void fused_model(const int* __restrict__ tokens,
                                                   const float* __restrict__ cptr,
                                                   float* __restrict__ out) {
  __shared__ float4 btab[NB];          // (kx, ky, v, cnt-as-float)
  __shared__ int    cnt[NB];
  __shared__ float4 ktab[RROWS];       // exact local keys (kx, ky, v, _)
  __shared__ int    dl[RROWS];
  __shared__ float  pm[4][RROWS], pd[4][RROWS], pn[4][RROWS];
  __shared__ float  rr0[RROWS], rr1[RROWS];
  __shared__ float  stab0[10], stab1[10], salpha[10], sv[10], sq0[10], sq1[10];

  const int tid = threadIdx.x;
  const int b = blockIdx.y;
  const int i0 = blockIdx.x * RROWS;
  const float cs = cptr[0];

  const double omega_d = 2.0 * M_PI / 19.0;
  const double phi_d = omega_d * 10.3;
  const double amp_d = log(10.0) / (cos(omega_d * 0.3) - cos(omega_d * 0.7));
  const double qkns_d = sqrt(amp_d / sqrt(2.0));
  const double attn_scale_d = (1.0 / sqrt(2.0)) * qkns_d * qkns_d;
  const float omega_f = (float)omega_d;
  const float c1 = (float)cos(phi_d);
  const float ns1 = (float)(-sin(phi_d));
  const float S2 = (float)attn_scale_d * 1.4426950408889634f;  // log2(e) folded
  const float vfac = (float)(-22.0 / sqrt(2.0));

  if (tid < NB) cnt[tid] = 0;
  if (tid < 10) {
    float d = (float)tid;
    float h0 = cs - d * d / cs;
    float h1 = -d;
    float inv = rsqrtf((h0 * h0 + h1 * h1) * 0.5f + 1e-6f);
    float x0 = h0 * inv, x1 = h1 * inv;
    stab0[tid] = h0;
    stab1[tid] = h1;
    salpha[tid] = x0 * rsqrtf((x0 * x0) * 0.5f + 1e-6f);
    sv[tid] = x1 * (vfac * cs);
    float q0 = x0 * c1, q1 = x0 * ns1;
    float invq = rsqrtf((q0 * q0 + q1 * q1) * 0.5f + 1e-6f);
    sq0[tid] = q0 * invq;
    sq1[tid] = q1 * invq;
  }
  __syncthreads();

  // Bucket reps (d, j mod 19) and exact local keys
  if (tid < NB) {
    if (tid < 190) {
      int d = tid / 19, r = tid - d * 19;
      float st, ct;
      sincosf((float)r * omega_f, &st, &ct);
      float al = salpha[d];
      btab[tid] = make_float4(al * ct, al * st, sv[d], 0.f);
    } else {
      btab[tid] = make_float4(0.f, 0.f, 0.f, 0.f);
    }
  }
  const int* tb = tokens + b * SEQ;
  if (tid < RROWS) {
    int j = i0 + tid;
    int d = tb[j];
    float st, ct;
    sincosf((float)j * omega_f, &st, &ct);
    float al = salpha[d];
    ktab[tid] = make_float4(al * ct, al * st, sv[d], 0.f);
    dl[tid] = d;
  }

  // Base histogram over j < i0 (int4 loads; i0 % 4 == 0 so chunks never straddle)
  for (int base = 0; base < i0; base += 1024) {
    int j4 = base + tid * 4;
    if (j4 < i0) {
      int4 t4 = *reinterpret_cast<const int4*>(tb + j4);
      int r = j4 % 19;
      atomicAdd(&cnt[t4.x * 19 + r], 1); r = (r + 1 < 19) ? r + 1 : 0;
      atomicAdd(&cnt[t4.y * 19 + r], 1); r = (r + 1 < 19) ? r + 1 : 0;
      atomicAdd(&cnt[t4.z * 19 + r], 1); r = (r + 1 < 19) ? r + 1 : 0;
      atomicAdd(&cnt[t4.w * 19 + r], 1);
    }
  }
  __syncthreads();
  if (tid < NB) btab[tid].w = (float)cnt[tid];
  __syncthreads();

  // Transposed attention: lane L owns row i0+L; wave splits buckets/tail 4-way.
  const int wid = tid >> 6;
  const int lane = tid & 63;
  const int i = i0 + lane;
  const int di = dl[lane];
  float st, ct;
  sincosf((float)i * omega_f, &st, &ct);
  const float qx = (sq0[di] * ct - sq1[di] * st) * S2;
  const float qy = (sq0[di] * st + sq1[di] * ct) * S2;

  const int boff = wid * GROUP;
  const int toff = wid * 16;

  // pass 1: subset max (sentinel -1e30 for empty/masked; never -inf -> no NaN)
  float m = -1e30f;
#pragma unroll 8
  for (int k = 0; k < GROUP; ++k) {
    float4 t = btab[boff + k];
    float l = fmaf(qx, t.x, qy * t.y);
    m = fmaxf(m, (t.w != 0.f) ? l : -1e30f);
  }
#pragma unroll
  for (int tt = 0; tt < 16; ++tt) {
    float4 kk = ktab[toff + tt];
    float l = fmaf(qx, kk.x, qy * kk.y);
    m = fmaxf(m, (toff + tt <= lane) ? l : -1e30f);
  }

  // pass 2: exp sums relative to subset max (masked logits -> -1e30 before exp2)
  float den = 0.f, num = 0.f;
#pragma unroll 8
  for (int k = 0; k < GROUP; ++k) {
    float4 t = btab[boff + k];
    float l = fmaf(qx, t.x, qy * t.y);
    l = (t.w != 0.f) ? l : -1e30f;
    float e = exp2f(l - m) * t.w;
    den += e;
    num = fmaf(e, t.z, num);
  }
#pragma unroll
  for (int tt = 0; tt < 16; ++tt) {
    float4 kk = ktab[toff + tt];
    float l = fmaf(qx, kk.x, qy * kk.y);
    float e = (toff + tt <= lane) ? exp2f(l - m) : 0.f;
    den += e;
    num = fmaf(e, kk.z, num);
  }
  pm[wid][lane] = m;
  pd[wid][lane] = den;
  pn[wid][lane] = num;
  __syncthreads();

  if (wid == 0) {
    float m0 = pm[0][lane], m1 = pm[1][lane], m2 = pm[2][lane], m3 = pm[3][lane];
    float M = fmaxf(fmaxf(m0, m1), fmaxf(m2, m3));   // wave 0 always real
    float s0 = exp2f(m0 - M), s1 = exp2f(m1 - M), s2 = exp2f(m2 - M), s3 = exp2f(m3 - M);
    float dn = fmaf(pd[0][lane], s0, fmaf(pd[1][lane], s1,
               fmaf(pd[2][lane], s2, pd[3][lane] * s3)));
    float nm = fmaf(pn[0][lane], s0, fmaf(pn[1][lane], s1,
               fmaf(pn[2][lane], s2, pn[3][lane] * s3)));
    const float o0 = nm / dn;

    // Elementwise epilogue (identical fp32 op order to passing R1/R2 kernels)
    const float h0 = stab0[di];
    const float h1 = stab1[di];
    const float h1a = h1 + o0;
    const float inv2 = rsqrtf((h0 * h0 + h1a * h1a) * 0.5f + 1e-6f);
    const float n0 = h0 * inv2, n1 = h1a * inv2;
    const float aa = -12.032f * cs;
    const float gc = 128.0f * cs;
    const float g0 = n0 * aa + n1 * gc;
    const float g1 = n0 * (aa - gc / cs) + n1 * gc;
    const float m0_ = (g0 / (1.f + expf(-g0))) * n0;
    const float m1_ = (g1 / (1.f + expf(-g1))) * n0;
    const float y1 = 0.390625f * (m1_ - m0_);
    const float h1b = h1a + y1;
    const float inv3 = rsqrtf((h0 * h0 + h1b * h1b) * 0.5f + 1e-6f);
    const float nw0 = (0.1f * cs) / 1.41421356237309515f;
    const float nw1 = -cs / 70.7106781186547524f;
    rr0[lane] = h0 * inv3 * nw0;
    rr1[lane] = h1b * inv3 * nw1;
  }
  __syncthreads();

  // Coalesced projection + store: 640 outputs across 256 threads
  const size_t obase = (size_t)(b * SEQ + i0) * 10;
  for (int e = tid; e < RROWS * 10; e += 256) {
    int row = e / 10;
    int col = e - row * 10;
    out[obase + e] = rr0[row] * stab0[col] + rr1[row] * stab1[col];
  }
}

extern "C" void kernel_launch(void* const* d_in, const int* in_sizes, int n_in,
                              void* d_out, int out_size, void* d_ws, size_t ws_size,
                              hipStream_t stream) {
  const int* tokens = (const int*)d_in[0];
  const float* c = (const float*)d_in[1];
  float* out = (float*)d_out;
  const int batches = in_sizes[0] / SEQ;   // 4
  dim3 grid(SEQ / RROWS, batches);         // 64 x 4 = 256 blocks, 1 per CU
  fused_model<<<grid, 256, 0, stream>>>(tokens, c, out);
}

// Round 4
// 9.777 us; speedup vs baseline: 4.9579x; 1.4896x over previous
//
#include <hip/hip_runtime.h>
#include <math.h>

#define SEQ 4096
#define RPB 32            // rows per block: 4 waves x 8 rows
#define NSLOT 40          // 19 (+class) + 19 (-class) + zero-class + pad

__global__ __launch_bounds__(256) void fused_model(const int* __restrict__ tokens,
                                                   const float* __restrict__ cptr,
                                                   float* __restrict__ out) {
  __shared__ int    cnt[192];
  __shared__ float4 btab[NSLOT];   // kx, ky, C (count), W (count-weighted v)
  __shared__ float4 ktab[RPB];     // exact local keys: kx, ky, v, -
  __shared__ int    dl[RPB];
  __shared__ float  salpha[10], sv[10], sq0[10], sq1[10];

  const int tid = threadIdx.x;
  const int b = blockIdx.y;
  const int i0 = blockIdx.x * RPB;
  const float cs = cptr[0];

  const double omega_d = 2.0 * M_PI / 19.0;
  const double phi_d = omega_d * 10.3;
  const double amp_d = log(10.0) / (cos(omega_d * 0.3) - cos(omega_d * 0.7));
  const double qkns_d = sqrt(amp_d / sqrt(2.0));
  const double attn_scale_d = (1.0 / sqrt(2.0)) * qkns_d * qkns_d;
  const float omega_f = (float)omega_d;
  const float c1 = (float)cos(phi_d);
  const float ns1 = (float)(-sin(phi_d));
  const float S2 = (float)attn_scale_d * 1.4426950408889634f;  // log2(e) folded
  const float vfac = (float)(-22.0 / sqrt(2.0));

  if (tid < 192) cnt[tid] = 0;
  if (tid < 10) {
    float d = (float)tid;
    float h0 = cs - d * d / cs;
    float h1 = -d;
    float inv = rsqrtf((h0 * h0 + h1 * h1) * 0.5f + 1e-6f);
    float x0 = h0 * inv, x1 = h1 * inv;
    salpha[tid] = x0 * rsqrtf((x0 * x0) * 0.5f + 1e-6f);
    sv[tid] = x1 * (vfac * cs);
    float q0 = x0 * c1, q1 = x0 * ns1;
    float invq = rsqrtf((q0 * q0 + q1 * q1) * 0.5f + 1e-6f);
    sq0[tid] = q0 * invq;
    sq1[tid] = q1 * invq;
  }
  __syncthreads();

  const int* tb = tokens + b * SEQ;

  // exact local keys for this block's 32 rows
  if (tid < RPB) {
    int j = i0 + tid;
    int d = tb[j];
    float st, ct;
    sincosf((float)j * omega_f, &st, &ct);
    float al = salpha[d];
    ktab[tid] = make_float4(al * ct, al * st, sv[d], 0.f);
    dl[tid] = d;
  }

  // histogram of j < i0 (i0 % 32 == 0, int4-aligned; <=4 iterations)
  for (int base = 0; base < i0; base += 1024) {
    int j4 = base + tid * 4;
    if (j4 < i0) {
      int4 t4 = *reinterpret_cast<const int4*>(tb + j4);
      int r = j4 % 19;
      atomicAdd(&cnt[t4.x * 19 + r], 1); r = (r + 1 < 19) ? r + 1 : 0;
      atomicAdd(&cnt[t4.y * 19 + r], 1); r = (r + 1 < 19) ? r + 1 : 0;
      atomicAdd(&cnt[t4.z * 19 + r], 1); r = (r + 1 < 19) ? r + 1 : 0;
      atomicAdd(&cnt[t4.w * 19 + r], 1);
    }
  }
  __syncthreads();

  // collapse (d, r) -> (sign-class, r): slots 0-18 = d==0 (+), 19-37 = d>=2 (-), 38 = d==1 (k==0), 39 pad
  if (tid < NSLOT) {
    float C = 0.f, W = 0.f, kx = 0.f, ky = 0.f;
    if (tid < 19) {
      int c = cnt[tid];
      C = (float)c; W = C * sv[0];
      float st, ct; sincosf((float)tid * omega_f, &st, &ct);
      kx = salpha[0] * ct; ky = salpha[0] * st;
    } else if (tid < 38) {
      int r = tid - 19;
      int s = 0; float w = 0.f;
#pragma unroll
      for (int d = 2; d < 10; ++d) { int c = cnt[d * 19 + r]; s += c; w += (float)c * sv[d]; }
      C = (float)s; W = w;
      float st, ct; sincosf((float)r * omega_f, &st, &ct);
      kx = salpha[2] * ct; ky = salpha[2] * st;
    } else if (tid == 38) {
      int s = 0;
#pragma unroll
      for (int r = 0; r < 19; ++r) s += cnt[19 + r];
      C = (float)s; W = C * sv[1];          // logit exactly 0 (k == 0)
    }
    btab[tid] = make_float4(kx, ky, C, W);
  }
  __syncthreads();

  // ---- decoupled per-wave attention: wave owns 8 rows, 8 lane-parts per row ----
  const int wid = tid >> 6;
  const int lane = tid & 63;
  const int row = lane & 7;
  const int part = lane >> 3;
  const int tmax = wid * 8 + row;          // tail indices t <= tmax are causal-valid
  const int i = i0 + tmax;
  const int di = dl[tmax];
  float st, ct;
  sincosf((float)i * omega_f, &st, &ct);
  const float qx = (sq0[di] * ct - sq1[di] * st) * S2;
  const float qy = (sq0[di] * st + sq1[di] * ct) * S2;

  // pass 1: max over this part's 5 slots + 4 tail keys (finite sentinel, no NaN)
  float m = -1e30f;
#pragma unroll
  for (int k = 0; k < 5; ++k) {
    float4 t = btab[part + k * 8];
    float l = fmaf(qx, t.x, qy * t.y);
    m = fmaxf(m, (t.z != 0.f) ? l : -1e30f);
  }
#pragma unroll
  for (int k = 0; k < 4; ++k) {
    int t = part + k * 8;
    float4 kk = ktab[t];
    float l = fmaf(qx, kk.x, qy * kk.y);
    m = fmaxf(m, (t <= tmax) ? l : -1e30f);
  }

  // pass 2: exp sums (masked slots pinned to -1e30 BEFORE exp2: avoids inf*0)
  float den = 0.f, num = 0.f;
#pragma unroll
  for (int k = 0; k < 5; ++k) {
    float4 t = btab[part + k * 8];
    float l = fmaf(qx, t.x, qy * t.y);
    l = (t.z != 0.f) ? l : -1e30f;
    float e = exp2f(l - m);
    den = fmaf(e, t.z, den);
    num = fmaf(e, t.w, num);
  }
#pragma unroll
  for (int k = 0; k < 4; ++k) {
    int t = part + k * 8;
    float4 kk = ktab[t];
    float l = fmaf(qx, kk.x, qy * kk.y);
    float e = (t <= tmax) ? exp2f(l - m) : 0.f;
    den += e;
    num = fmaf(e, kk.z, num);
  }

  // merge the 8 parts: butterfly over lane bits 3..5
#pragma unroll
  for (int off = 8; off < 64; off <<= 1) {
    float mo = __shfl_xor(m, off);
    float dno = __shfl_xor(den, off);
    float nmo = __shfl_xor(num, off);
    float M = fmaxf(m, mo);
    float sa = exp2f(m - M), sb = exp2f(mo - M);
    den = fmaf(den, sa, dno * sb);
    num = fmaf(num, sa, nmo * sb);
    m = M;
  }
  const float o0 = num / den;

  // epilogue: all lanes compute (redundant across parts), identical fp32 op order
  const float df = (float)di;
  const float h0 = cs - df * df / cs;
  const float h1 = -df;
  const float h1a = h1 + o0;
  const float inv2 = rsqrtf((h0 * h0 + h1a * h1a) * 0.5f + 1e-6f);
  const float n0 = h0 * inv2, n1 = h1a * inv2;
  const float aa = -12.032f * cs;
  const float gc = 128.0f * cs;
  const float g0 = n0 * aa + n1 * gc;
  const float g1 = n0 * (aa - gc / cs) + n1 * gc;
  const float m0_ = (g0 / (1.f + expf(-g0))) * n0;
  const float m1_ = (g1 / (1.f + expf(-g1))) * n0;
  const float y1 = 0.390625f * (m1_ - m0_);
  const float h1b = h1a + y1;
  const float inv3 = rsqrtf((h0 * h0 + h1b * h1b) * 0.5f + 1e-6f);
  const float nw0 = (0.1f * cs) / 1.41421356237309515f;
  const float nw1 = -cs / 70.7106781186547524f;
  const float r0 = h0 * inv3 * nw0;
  const float r1 = h1b * inv3 * nw1;

  // store: part p writes col p; parts 0,1 also write cols 8,9
  const size_t ob = (size_t)(b * SEQ + i) * 10;
  {
    float dc = (float)part;
    out[ob + part] = r0 * (cs - dc * dc / cs) + r1 * (-dc);
    if (part < 2) {
      float dc2 = (float)(8 + part);
      out[ob + 8 + part] = r0 * (cs - dc2 * dc2 / cs) + r1 * (-dc2);
    }
  }
}

extern "C" void kernel_launch(void* const* d_in, const int* in_sizes, int n_in,
                              void* d_out, int out_size, void* d_ws, size_t ws_size,
                              hipStream_t stream) {
  const int* tokens = (const int*)d_in[0];
  const float* c = (const float*)d_in[1];
  float* out = (float*)d_out;
  const int batches = in_sizes[0] / SEQ;   // 4
  dim3 grid(SEQ / RPB, batches);           // 128 x 4 = 512 blocks, 2 per CU
  fused_model<<<grid, 256, 0, stream>>>(tokens, c, out);
}

// Round 5
// 9.753 us; speedup vs baseline: 4.9700x; 1.0024x over previous
//
#include <hip/hip_runtime.h>
#include <math.h>

#define SEQ 4096
#define RPB 32            // rows per block: 4 waves x 8 rows
#define NSLOT 40          // 19 (+class) + 19 (-class) + zero-class + pad

// sin/cos of (2*pi * idx/19) via hardware v_sin/v_cos (input in revolutions)
__device__ __forceinline__ void sincos19(float idx, float* s, float* c) {
  float rev = idx * (1.0f / 19.0f);
  rev -= floorf(rev);
  *s = __builtin_amdgcn_sinf(rev);
  *c = __builtin_amdgcn_cosf(rev);
}

__global__ __launch_bounds__(256) void fused_model(const int* __restrict__ tokens,
                                                   const float* __restrict__ cptr,
                                                   float* __restrict__ out) {
  __shared__ int    cnt[192];
  __shared__ float4 btab[NSLOT];   // kx, ky, C (count), W (count-weighted v)
  __shared__ float4 ktab[RPB];     // exact local keys: kx, ky, v, -
  __shared__ int    dl[RPB];
  __shared__ float  salpha[10], sv[10], sq0[10], sq1[10];

  const int tid = threadIdx.x;
  const int b = blockIdx.y;
  const int i0 = blockIdx.x * RPB;
  const float cs = cptr[0];
  const int* tb = tokens + b * SEQ;

  // ---- prefetch global token data; latency hides under init + barrier ----
  int dloc = 0;
  if (tid < RPB) dloc = tb[i0 + tid];
  const int tj = tid * 4;
  int4 tt[4];
#pragma unroll
  for (int it = 0; it < 4; ++it) {
    int j4 = it * 1024 + tj;
    if (j4 < i0) tt[it] = *reinterpret_cast<const int4*>(tb + j4);
  }

  // Derived constants (double, constant-folded)
  const double omega_d = 2.0 * M_PI / 19.0;
  const double phi_d = omega_d * 10.3;
  const double amp_d = log(10.0) / (cos(omega_d * 0.3) - cos(omega_d * 0.7));
  const double qkns_d = sqrt(amp_d / sqrt(2.0));
  const double attn_scale_d = (1.0 / sqrt(2.0)) * qkns_d * qkns_d;
  const float c1 = (float)cos(phi_d);
  const float ns1 = (float)(-sin(phi_d));
  const float S2 = (float)attn_scale_d * 1.4426950408889634f;  // log2(e) folded
  const float vfac = (float)(-22.0 / sqrt(2.0));

  // ---- P0: zero counters + token tables ----
  if (tid < 192) cnt[tid] = 0;
  if (tid < 10) {
    float d = (float)tid;
    float h0 = cs - d * d / cs;
    float h1 = -d;
    float inv = rsqrtf((h0 * h0 + h1 * h1) * 0.5f + 1e-6f);
    float x0 = h0 * inv, x1 = h1 * inv;
    salpha[tid] = x0 * rsqrtf((x0 * x0) * 0.5f + 1e-6f);
    sv[tid] = x1 * (vfac * cs);
    float q0 = x0 * c1, q1 = x0 * ns1;
    float invq = rsqrtf((q0 * q0 + q1 * q1) * 0.5f + 1e-6f);
    sq0[tid] = q0 * invq;
    sq1[tid] = q1 * invq;
  }
  __syncthreads();

  // ---- P1: local keys + histogram (registers -> LDS atomics) ----
  if (tid < RPB) {
    float sj, cj;
    sincos19((float)(i0 + tid), &sj, &cj);
    float al = salpha[dloc];
    ktab[tid] = make_float4(al * cj, al * sj, sv[dloc], 0.f);
    dl[tid] = dloc;
  }
  {
    int r = tj % 19;
#pragma unroll
    for (int it = 0; it < 4; ++it) {
      int j4 = it * 1024 + tj;
      if (j4 < i0) {
        int q = r;
        atomicAdd(&cnt[tt[it].x * 19 + q], 1); q = (q + 1 < 19) ? q + 1 : 0;
        atomicAdd(&cnt[tt[it].y * 19 + q], 1); q = (q + 1 < 19) ? q + 1 : 0;
        atomicAdd(&cnt[tt[it].z * 19 + q], 1); q = (q + 1 < 19) ? q + 1 : 0;
        atomicAdd(&cnt[tt[it].w * 19 + q], 1);
      }
      r = (r >= 2) ? r - 2 : r + 17;   // (r + 1024) mod 19
    }
  }
  __syncthreads();

  // ---- P2: collapse (d, r) -> (sign-class, r) ----
  if (tid < NSLOT) {
    float C = 0.f, W = 0.f, kx = 0.f, ky = 0.f;
    if (tid < 19) {
      int c = cnt[tid];
      C = (float)c; W = C * sv[0];
      float sr, cr; sincos19((float)tid, &sr, &cr);
      kx = salpha[0] * cr; ky = salpha[0] * sr;
    } else if (tid < 38) {
      int r = tid - 19;
      int s = 0; float w = 0.f;
#pragma unroll
      for (int d = 2; d < 10; ++d) { int c = cnt[d * 19 + r]; s += c; w += (float)c * sv[d]; }
      C = (float)s; W = w;
      float sr, cr; sincos19((float)r, &sr, &cr);
      kx = salpha[2] * cr; ky = salpha[2] * sr;
    } else if (tid == 38) {
      int s = 0;
#pragma unroll
      for (int r = 0; r < 19; ++r) s += cnt[19 + r];
      C = (float)s; W = C * sv[1];          // k == 0: logit exactly 0
    }
    btab[tid] = make_float4(kx, ky, C, W);
  }
  __syncthreads();

  // ---- P3: attention, wave-decoupled; 8 rows x 8 parts per wave ----
  const int wid = tid >> 6;
  const int lane = tid & 63;
  const int row = lane & 7;
  const int part = lane >> 3;
  const int tmax = wid * 8 + row;
  const int i = i0 + tmax;
  const int di = dl[tmax];
  float sti, cti;
  sincos19((float)i, &sti, &cti);
  const float qx = (sq0[di] * cti - sq1[di] * sti) * S2;
  const float qy = (sq0[di] * sti + sq1[di] * cti) * S2;

  // preload fragments (LDS broadcast reads, conflict-free)
  float4 sl0 = btab[part], sl1 = btab[part + 8], sl2 = btab[part + 16],
         sl3 = btab[part + 24], sl4 = btab[part + 32];
  float4 tl0 = ktab[part], tl1 = ktab[part + 8], tl2 = ktab[part + 16],
         tl3 = ktab[part + 24];

  // single logit pass into registers (masked to finite sentinel)
  float l0 = (sl0.z != 0.f) ? fmaf(qx, sl0.x, qy * sl0.y) : -1e30f;
  float l1 = (sl1.z != 0.f) ? fmaf(qx, sl1.x, qy * sl1.y) : -1e30f;
  float l2 = (sl2.z != 0.f) ? fmaf(qx, sl2.x, qy * sl2.y) : -1e30f;
  float l3 = (sl3.z != 0.f) ? fmaf(qx, sl3.x, qy * sl3.y) : -1e30f;
  float l4 = (sl4.z != 0.f) ? fmaf(qx, sl4.x, qy * sl4.y) : -1e30f;
  float t0 = (part      <= tmax) ? fmaf(qx, tl0.x, qy * tl0.y) : -1e30f;
  float t1 = (part + 8  <= tmax) ? fmaf(qx, tl1.x, qy * tl1.y) : -1e30f;
  float t2 = (part + 16 <= tmax) ? fmaf(qx, tl2.x, qy * tl2.y) : -1e30f;
  float t3 = (part + 24 <= tmax) ? fmaf(qx, tl3.x, qy * tl3.y) : -1e30f;

  // row max: in-register tree, then butterfly across the 8 parts
  float m = fmaxf(fmaxf(fmaxf(l0, l1), fmaxf(l2, l3)),
                  fmaxf(fmaxf(l4, t0), fmaxf(fmaxf(t1, t2), t3)));
#pragma unroll
  for (int off = 8; off < 64; off <<= 1) m = fmaxf(m, __shfl_xor(m, off));

  // single exp pass (masked entries: exp2(-1e30 - m) == 0, no NaN possible)
  float den = 0.f, num = 0.f;
  {
    float e;
    e = exp2f(l0 - m); den = fmaf(e, sl0.z, den); num = fmaf(e, sl0.w, num);
    e = exp2f(l1 - m); den = fmaf(e, sl1.z, den); num = fmaf(e, sl1.w, num);
    e = exp2f(l2 - m); den = fmaf(e, sl2.z, den); num = fmaf(e, sl2.w, num);
    e = exp2f(l3 - m); den = fmaf(e, sl3.z, den); num = fmaf(e, sl3.w, num);
    e = exp2f(l4 - m); den = fmaf(e, sl4.z, den); num = fmaf(e, sl4.w, num);
    e = exp2f(t0 - m); den += e; num = fmaf(e, tl0.z, num);
    e = exp2f(t1 - m); den += e; num = fmaf(e, tl1.z, num);
    e = exp2f(t2 - m); den += e; num = fmaf(e, tl2.z, num);
    e = exp2f(t3 - m); den += e; num = fmaf(e, tl3.z, num);
  }
#pragma unroll
  for (int off = 8; off < 64; off <<= 1) {
    den += __shfl_xor(den, off);
    num += __shfl_xor(num, off);
  }
  const float o0 = num / den;

  // ---- epilogue (identical fp32 op order to passing R1-R4 kernels) ----
  const float df = (float)di;
  const float h0 = cs - df * df / cs;
  const float h1 = -df;
  const float h1a = h1 + o0;
  const float inv2 = rsqrtf((h0 * h0 + h1a * h1a) * 0.5f + 1e-6f);
  const float n0 = h0 * inv2, n1 = h1a * inv2;
  const float aa = -12.032f * cs;
  const float gc = 128.0f * cs;
  const float g0 = n0 * aa + n1 * gc;
  const float g1 = n0 * (aa - gc / cs) + n1 * gc;
  const float m0_ = (g0 / (1.f + expf(-g0))) * n0;
  const float m1_ = (g1 / (1.f + expf(-g1))) * n0;
  const float y1 = 0.390625f * (m1_ - m0_);
  const float h1b = h1a + y1;
  const float inv3 = rsqrtf((h0 * h0 + h1b * h1b) * 0.5f + 1e-6f);
  const float nw0 = (0.1f * cs) / 1.41421356237309515f;
  const float nw1 = -cs / 70.7106781186547524f;
  const float r0 = h0 * inv3 * nw0;
  const float r1 = h1b * inv3 * nw1;

  // store: part p writes col p; parts 0,1 also write cols 8,9
  const size_t ob = (size_t)(b * SEQ + i) * 10;
  {
    float dc = (float)part;
    out[ob + part] = r0 * (cs - dc * dc / cs) + r1 * (-dc);
    if (part < 2) {
      float dc2 = (float)(8 + part);
      out[ob + 8 + part] = r0 * (cs - dc2 * dc2 / cs) + r1 * (-dc2);
    }
  }
}

extern "C" void kernel_launch(void* const* d_in, const int* in_sizes, int n_in,
                              void* d_out, int out_size, void* d_ws, size_t ws_size,
                              hipStream_t stream) {
  const int* tokens = (const int*)d_in[0];
  const float* c = (const float*)d_in[1];
  float* out = (float*)d_out;
  const int batches = in_sizes[0] / SEQ;   // 4
  dim3 grid(SEQ / RPB, batches);           // 128 x 4 = 512 blocks, 2 per CU
  fused_model<<<grid, 256, 0, stream>>>(tokens, c, out);
}